// Round 1
// baseline (115.914 us; speedup 1.0000x reference)
//
#include <hip/hip_runtime.h>

// RelativePositionEncoding: out[i,j,c] = W[dres(i,j)][c] + W[65+dtok(i,j)][c]
//                                      + same_entity(i,j)*W[130][c] + W[131+dch(i,j)][c]
// B=1, N=1024, CZ=128, W: [136][128] fp32. Output: [1024][1024][128] fp32 = 512 MiB.
// Pure HBM-write-bound; W staged in LDS (69,632 B), 2 blocks/CU.

constexpr int NTOK = 1024;
constexpr int ROWS = 136;          // 65 rel_pos | 65 rel_token | 1 entity | 5 rel_chain
constexpr int THREADS = 512;
constexpr int GRID = 1024;         // 524,288 threads total; each does 64 float4 stores

__global__ __launch_bounds__(THREADS)
void relpos_kernel(const int* __restrict__ asym,
                   const int* __restrict__ resid,
                   const int* __restrict__ ent,
                   const int* __restrict__ tok,
                   const int* __restrict__ sym,
                   const float* __restrict__ W,
                   float4* __restrict__ outv)
{
    __shared__ float4 sW[ROWS * 32];   // 136 rows x 32 float4 = 69,632 B
    const int tid = threadIdx.x;

    // ---- stage W into LDS (coalesced float4 copy) ----
    const float4* Wv = reinterpret_cast<const float4*>(W);
    for (int k = tid; k < ROWS * 32; k += THREADS)
        sW[k] = Wv[k];
    __syncthreads();

    // ---- work decomposition ----
    // global thread id t in [0, 524288): c4 = t&31 (float4 within channel dim),
    // pair p = t>>5; per-iteration stride = 16384 pairs so j = p&1023 is FIXED
    // per thread and i steps by 16. 64 iterations cover all 2^20 pairs.
    const int t  = blockIdx.x * THREADS + tid;
    const int c4 = t & 31;
    const int p0 = t >> 5;
    const int j  = p0 & 1023;
    int i        = p0 >> 10;           // in [0,16)

    const int aj = asym[j];
    const int rj = resid[j];
    const int ej = ent[j];
    const int tj = tok[j];
    const int sj = sym[j];

    const float4 vE = sW[130 * 32 + c4];   // entity row hoisted to registers

    size_t oidx = (size_t)t;               // float4 index = p*32 + c4
    #pragma unroll 4
    for (int it = 0; it < 64; ++it) {
        const int ai = asym[i];
        const int ri = resid[i];
        const int ei = ent[i];
        const int ti = tok[i];
        const int si = sym[i];

        const bool sc = (ai == aj);
        const bool sr = (ri == rj);

        int dres = min(max(rj - ri + 32, 0), 64);
        int dtok = min(max(tj - ti + 32, 0), 64);
        int dch  = min(max(sj - si + 2, 0), 4);
        if (sc)        { dres = 64; dch = 4; }
        if (sc || sr)  { dtok = 64; }
        const float se = (ei == ej) ? 1.0f : 0.0f;

        const float4 v0 = sW[dres * 32 + c4];
        const float4 v1 = sW[(65 + dtok) * 32 + c4];
        const float4 v3 = sW[(131 + dch) * 32 + c4];

        // match reference order: ((t0 + t1) + se*w130) + t3
        float4 r;
        r.x = fmaf(se, vE.x, v0.x + v1.x) + v3.x;
        r.y = fmaf(se, vE.y, v0.y + v1.y) + v3.y;
        r.z = fmaf(se, vE.z, v0.z + v1.z) + v3.z;
        r.w = fmaf(se, vE.w, v0.w + v1.w) + v3.w;

        outv[oidx] = r;
        oidx += (size_t)GRID * THREADS;    // 524,288 float4
        i += 16;
    }
}

extern "C" void kernel_launch(void* const* d_in, const int* in_sizes, int n_in,
                              void* d_out, int out_size, void* d_ws, size_t ws_size,
                              hipStream_t stream) {
    const int*   asym  = (const int*)  d_in[0];
    const int*   resid = (const int*)  d_in[1];
    const int*   ent   = (const int*)  d_in[2];
    const int*   tok   = (const int*)  d_in[3];
    const int*   sym   = (const int*)  d_in[4];
    const float* W     = (const float*)d_in[5];
    float4* outv = (float4*)d_out;

    relpos_kernel<<<GRID, THREADS, 0, stream>>>(asym, resid, ent, tok, sym, W, outv);
}